// Round 8
// baseline (136.041 us; speedup 1.0000x reference)
//
#include <hip/hip_runtime.h>

// SpikeKernelLoss: loss = 0.5 * sum((outputs - psp(target))^2)
// psp: syn[t] = syn[t-1]*0.8 + target[t]; psp[t] = syn[t]/5
// [128, 2048, 100] f32.
//
// R8: R5/R6/R7 converged at bench ~40 us with 3 different structures ->
// main (~36 us) is at ~93% of the 6.29 TB/s copy ceiling (210 MB, half
// L3-resident). Remaining slack = second-kernel tail tax (~4-5 us).
// Fuse: last-arriving block (atomic counter) reduces the 4096 block
// partials in the same kernel. Main loop identical to R7.

constexpr int NF4 = 25;            // float4 per stream per row (T=100)

typedef __attribute__((ext_vector_type(4))) float f32x4;

constexpr float pwf(double b, int n) {
    double r = 1.0; for (int i = 0; i < n; ++i) r *= b; return (float)r;
}
// w_t = 0.2 * 0.8^(t+1) for local t = 0..3
constexpr float W0 = 0.16f, W1 = 0.128f, W2 = 0.1024f, W3 = 0.08192f;
constexpr float CC = (float)(0.16*0.16 + 0.128*0.128 + 0.1024*0.1024 + 0.08192*0.08192);

constexpr int NBLOCKS = 4096;

__global__ __launch_bounds__(256) void spike_loss_fused(
    const float* __restrict__ outs, const float* __restrict__ tgt,
    float* __restrict__ bsums, int* __restrict__ counter,
    float* __restrict__ out, int nrows)
{
    const int g = threadIdx.x & 31;                                  // lane in 32-group
    const int grp0 = (blockIdx.x * blockDim.x + threadIdx.x) >> 5;   // global group id
    const int ngroups = (gridDim.x * blockDim.x) >> 5;
    const bool act = (g < NF4);

    float total = 0.0f;
    for (int row = grp0; row < nrows; row += ngroups) {
        // Lane-contiguous loads: lanes 0..24 cover the row's 400B span.
        f32x4 tv = {0.f, 0.f, 0.f, 0.f}, ov = {0.f, 0.f, 0.f, 0.f};
        size_t base = (size_t)row * NF4 + g;
        if (act) {
            tv = reinterpret_cast<const f32x4*>(tgt)[base];
            ov = reinterpret_cast<const f32x4*>(outs)[base];
        }
        // Local 4-step scan from syn=0; A = sum d^2, B = sum d*w_t.
        float syn, d, A, B;
        syn = tv.x;                  d = fmaf(syn, -0.2f, ov.x); A = d * d;         B = d * W0;
        syn = fmaf(syn, 0.8f, tv.y); d = fmaf(syn, -0.2f, ov.y); A = fmaf(d, d, A); B = fmaf(d, W1, B);
        syn = fmaf(syn, 0.8f, tv.z); d = fmaf(syn, -0.2f, ov.z); A = fmaf(d, d, A); B = fmaf(d, W2, B);
        syn = fmaf(syn, 0.8f, tv.w); d = fmaf(syn, -0.2f, ov.w); A = fmaf(d, d, A); B = fmaf(d, W3, B);

        // Exclusive weighted prefix of syn across the 32-group:
        // s_g = sum_{i<g} syn_i * 0.4096^(g-1-i). (Idle lanes hold syn=0.)
        float e = __shfl_up(syn, 1, 32);
        e = (g >= 1) ? e : 0.0f;
        #pragma unroll
        for (int off = 1; off < 32; off <<= 1) {
            float v = __shfl_up(e, off, 32);
            float m = fmaf(v, pwf(0.4096, off), e);
            e = (g >= off) ? m : e;
        }
        float s = e;
        // True contribution with incoming carry s: A - 2sB + s^2*C.
        float contrib = fmaf(s * s, CC, fmaf(-2.0f * s, B, A));
        total += act ? contrib : 0.0f;
    }

    // wave (64-lane) reduction, then cross-wave via LDS
    #pragma unroll
    for (int off = 32; off > 0; off >>= 1) total += __shfl_down(total, off, 64);
    __shared__ float wsum[4];
    __shared__ int lastflag;
    int lane = threadIdx.x & 63;
    int wid  = threadIdx.x >> 6;
    if (lane == 0) wsum[wid] = total;
    __syncthreads();
    if (threadIdx.x == 0) {
        float bs = wsum[0] + wsum[1] + wsum[2] + wsum[3];
        bsums[blockIdx.x] = bs;
        __threadfence();                      // release: partial visible device-wide
        int old = atomicAdd(counter, 1);      // device-scope by default
        lastflag = (old == (int)gridDim.x - 1);
    }
    __syncthreads();

    if (lastflag) {
        __threadfence();                      // acquire side
        float acc = 0.0f;
        for (int i = threadIdx.x; i < (int)gridDim.x; i += blockDim.x) {
            acc += __hip_atomic_load(&bsums[i], __ATOMIC_RELAXED,
                                     __HIP_MEMORY_SCOPE_AGENT);
        }
        #pragma unroll
        for (int off = 32; off > 0; off >>= 1) acc += __shfl_down(acc, off, 64);
        __syncthreads();                      // wsum reuse
        if (lane == 0) wsum[wid] = acc;
        __syncthreads();
        if (threadIdx.x == 0) {
            out[0] = 0.5f * (wsum[0] + wsum[1] + wsum[2] + wsum[3]);
        }
    }
}

extern "C" void kernel_launch(void* const* d_in, const int* in_sizes, int n_in,
                              void* d_out, int out_size, void* d_ws, size_t ws_size,
                              hipStream_t stream) {
    const float* outs = (const float*)d_in[0];   // outputs [128,2048,100]
    const float* tgt  = (const float*)d_in[1];   // target  [128,2048,100]
    float* out = (float*)d_out;                  // scalar loss

    // ws layout: [0..3] counter (int), [256..) block partials
    int*   counter = (int*)d_ws;
    float* bsums   = (float*)((char*)d_ws + 256);

    int nrows = in_sizes[0] / 100;               // 262144

    hipMemsetAsync(counter, 0, sizeof(int), stream);   // graph-capturable
    spike_loss_fused<<<NBLOCKS, 256, 0, stream>>>(outs, tgt, bsums, counter,
                                                  out, nrows);
}

// Round 9
// 40.310 us; speedup vs baseline: 3.3749x; 3.3749x over previous
//
#include <hip/hip_runtime.h>

// SpikeKernelLoss: loss = 0.5 * sum((outputs - psp(target))^2)
// psp: syn[t] = syn[t-1]*0.8 + target[t]; psp[t] = syn[t]/5
// [128, 2048, 100] f32.
//
// R9 = exact revert to R7 (best: 40.6 us). R8's fused last-block-reduce
// regressed 3.3x: per-block __threadfence (L2 writeback) + 4096 serialized
// same-address atomicAdds stalled the whole dispatch (VALUBusy 13.9->5.6%,
// same FETCH). Two-kernel structure: main at ~5.7 TB/s effective (~90% of
// 6.29 TB/s ceiling) + ~4 us reduce-kernel tail.
//
// Main-loop design (R7): 32-lane group per row, lane g loads float4 g
// (lane-contiguous). Per-thread 4-step local scan with compile-time
// weights; row carry via 5-step weighted Kogge-Stone prefix
// (__shfl_up width 32, scale 0.4096^off). contrib = A - 2sB + s^2*C.

constexpr int NF4 = 25;            // float4 per stream per row (T=100)

typedef __attribute__((ext_vector_type(4))) float f32x4;

constexpr float pwf(double b, int n) {
    double r = 1.0; for (int i = 0; i < n; ++i) r *= b; return (float)r;
}
// w_t = 0.2 * 0.8^(t+1) for local t = 0..3
constexpr float W0 = 0.16f, W1 = 0.128f, W2 = 0.1024f, W3 = 0.08192f;
constexpr float CC = (float)(0.16*0.16 + 0.128*0.128 + 0.1024*0.1024 + 0.08192*0.08192);

__global__ __launch_bounds__(256) void spike_loss_main(
    const float* __restrict__ outs, const float* __restrict__ tgt,
    float* __restrict__ block_sums, int nrows)
{
    const int g = threadIdx.x & 31;                                  // lane in 32-group
    const int grp0 = (blockIdx.x * blockDim.x + threadIdx.x) >> 5;   // global group id
    const int ngroups = (gridDim.x * blockDim.x) >> 5;
    const bool act = (g < NF4);

    float total = 0.0f;
    for (int row = grp0; row < nrows; row += ngroups) {
        // Lane-contiguous loads: lanes 0..24 cover the row's 400B span.
        f32x4 tv = {0.f, 0.f, 0.f, 0.f}, ov = {0.f, 0.f, 0.f, 0.f};
        size_t base = (size_t)row * NF4 + g;
        if (act) {
            tv = reinterpret_cast<const f32x4*>(tgt)[base];
            ov = reinterpret_cast<const f32x4*>(outs)[base];
        }
        // Local 4-step scan from syn=0; A = sum d^2, B = sum d*w_t.
        float syn, d, A, B;
        syn = tv.x;                  d = fmaf(syn, -0.2f, ov.x); A = d * d;         B = d * W0;
        syn = fmaf(syn, 0.8f, tv.y); d = fmaf(syn, -0.2f, ov.y); A = fmaf(d, d, A); B = fmaf(d, W1, B);
        syn = fmaf(syn, 0.8f, tv.z); d = fmaf(syn, -0.2f, ov.z); A = fmaf(d, d, A); B = fmaf(d, W2, B);
        syn = fmaf(syn, 0.8f, tv.w); d = fmaf(syn, -0.2f, ov.w); A = fmaf(d, d, A); B = fmaf(d, W3, B);

        // Exclusive weighted prefix of syn across the 32-group:
        // s_g = sum_{i<g} syn_i * 0.4096^(g-1-i). (Idle lanes hold syn=0.)
        float e = __shfl_up(syn, 1, 32);
        e = (g >= 1) ? e : 0.0f;
        #pragma unroll
        for (int off = 1; off < 32; off <<= 1) {
            float v = __shfl_up(e, off, 32);
            float m = fmaf(v, pwf(0.4096, off), e);
            e = (g >= off) ? m : e;
        }
        float s = e;
        // True contribution with incoming carry s: A - 2sB + s^2*C.
        float contrib = fmaf(s * s, CC, fmaf(-2.0f * s, B, A));
        total += act ? contrib : 0.0f;
    }

    // wave (64-lane) reduction, then cross-wave via LDS
    #pragma unroll
    for (int off = 32; off > 0; off >>= 1) total += __shfl_down(total, off, 64);
    __shared__ float wsum[4];
    int lane = threadIdx.x & 63;
    int wid  = threadIdx.x >> 6;
    if (lane == 0) wsum[wid] = total;
    __syncthreads();
    if (threadIdx.x == 0) {
        block_sums[blockIdx.x] = wsum[0] + wsum[1] + wsum[2] + wsum[3];
    }
}

__global__ __launch_bounds__(256) void spike_loss_reduce(
    const float* __restrict__ block_sums, float* __restrict__ out, int n)
{
    float acc = 0.0f;
    for (int i = threadIdx.x; i < n; i += 256) acc += block_sums[i];
    #pragma unroll
    for (int off = 32; off > 0; off >>= 1) acc += __shfl_down(acc, off, 64);
    __shared__ float wsum[4];
    int lane = threadIdx.x & 63;
    int wid  = threadIdx.x >> 6;
    if (lane == 0) wsum[wid] = acc;
    __syncthreads();
    if (threadIdx.x == 0) {
        out[0] = 0.5f * (wsum[0] + wsum[1] + wsum[2] + wsum[3]);
    }
}

extern "C" void kernel_launch(void* const* d_in, const int* in_sizes, int n_in,
                              void* d_out, int out_size, void* d_ws, size_t ws_size,
                              hipStream_t stream) {
    const float* outs = (const float*)d_in[0];   // outputs [128,2048,100]
    const float* tgt  = (const float*)d_in[1];   // target  [128,2048,100]
    float* out   = (float*)d_out;                // scalar loss
    float* bsums = (float*)d_ws;                 // per-block partials

    int nrows  = in_sizes[0] / 100;              // 262144
    int blocks = 4096;                           // 32768 groups, 8 rows/group

    spike_loss_main<<<blocks, 256, 0, stream>>>(outs, tgt, bsums, nrows);
    spike_loss_reduce<<<1, 256, 0, stream>>>(bsums, out, blocks);
}